// Round 7
// baseline (272.735 us; speedup 1.0000x reference)
//
#include <hip/hip_runtime.h>
#include <hip/hip_bf16.h>

#define NPOS 4096          // 64*64 positions
#define CD   64            // channels
#define NB   4             // batch
#define PADW 66
#define PADN (66*66)       // padded positions (zero halo)
#define NSEG 4             // attention n-split
#define NT   (NPOS / NSEG / 64)
#define LOG2E 1.4426950408889634f

extern "C" __device__ float __ocml_exp2_f32(float);

typedef __bf16 bf16x8_t __attribute__((ext_vector_type(8)));
typedef float  f32x4_t  __attribute__((ext_vector_type(4)));

static __device__ __forceinline__ unsigned short f2bf(float f) {
    return __builtin_bit_cast(unsigned short, __float2bfloat16(f));
}

static __device__ __forceinline__ void gload_lds16(const void* g, void* l) {
    __builtin_amdgcn_global_load_lds(
        (const __attribute__((address_space(1))) void*)g,
        (__attribute__((address_space(3))) void*)l, 16, 0, 0);
}

static __device__ __forceinline__ unsigned cvtpk_bf16(float lo, float hi) {
    unsigned r;
    asm("v_cvt_pk_bf16_f32 %0, %1, %2" : "=v"(r) : "v"(lo), "v"(hi));
    return r;
}

// ---------------------------------------------------------------------------
// prep: fused {halo-zero, weight-repack, input-pack} in one launch.
// grid 672 = 16 halo + 144 wrepack + 512 pack. block 256.
// ---------------------------------------------------------------------------
__global__ __launch_bounds__(256) void prep_kernel(
    const float* __restrict__ x, const float* __restrict__ y,
    const float* __restrict__ qw, const float* __restrict__ rkw,
    const float* __restrict__ rvw, const float* __restrict__ ikw,
    const float* __restrict__ ivw, const float* __restrict__ srw,
    const float* __restrict__ qs, const float* __restrict__ rks,
    const float* __restrict__ rvs, const float* __restrict__ iks,
    const float* __restrict__ ivs, const float* __restrict__ srs,
    unsigned short* __restrict__ pads, unsigned short* __restrict__ Wf)
{
    const int bx = blockIdx.x;
    if (bx < 16) {
        unsigned short* p = pads + (size_t)bx * PADN * CD;
        const uint4 z = make_uint4(0, 0, 0, 0);
        for (int idx = threadIdx.x; idx < 260 * 8; idx += 256) {
            const int pi = idx >> 3, chn = idx & 7;
            int pos;
            if (pi < 66)       pos = pi;
            else if (pi < 132) pos = 65 * PADW + (pi - 66);
            else { const int rem = pi - 132;
                   pos = (1 + (rem >> 1)) * PADW + ((rem & 1) ? 65 : 0); }
            *(uint4*)(p + (size_t)pos * CD + chn * 8) = z;
        }
        return;
    }
    if (bx < 160) {
        const int f = bx - 16;
        const float* w; const float* s; int cin, local;
        if (f < 36)       { w = qw;  s = qs;  cin = 128; local = f; }
        else if (f < 54)  { w = rkw; s = rks; cin = 64;  local = f - 36; }
        else if (f < 72)  { w = rvw; s = rvs; cin = 64;  local = f - 54; }
        else if (f < 90)  { w = ikw; s = iks; cin = 64;  local = f - 72; }
        else if (f < 108) { w = ivw; s = ivs; cin = 64;  local = f - 90; }
        else              { w = srw; s = srs; cin = 128; local = f - 108; }
        const int src = (cin == 128) ? local / 18 : 0;
        const int rem = (cin == 128) ? local % 18 : local;
        const int tap = rem >> 1, kt = rem & 1;
        const int t = threadIdx.x, cot = t >> 6, l = t & 63;
        const int co = cot * 16 + (l & 15);
        const float kmul = ((f >= 36 && f < 54) || (f >= 72 && f < 90)) ? LOG2E : 1.0f;
        const float sc = s[co] * kmul;
        unsigned short us[8];
#pragma unroll
        for (int e = 0; e < 8; ++e) {
            const int ci = src * 64 + kt * 32 + ((l >> 4) * 8) + e;
            us[e] = f2bf(w[((size_t)co * cin + ci) * 9 + tap] * sc);
        }
        *(uint4*)(Wf + ((size_t)(f * 4 + cot) * 64 + l) * 8) = *(uint4*)us;
        return;
    }
    {
        const int idx = bx - 160;
        const int h = idx & 63, b = (idx >> 6) & 3, src = idx >> 8;
        const float* in = src ? y : x;
        unsigned short* out = pads + (size_t)src * NB * PADN * CD;
        __shared__ float t[64][65];
        const int tt = threadIdx.x;
        {
            const int ci = tt >> 2, w0 = (tt & 3) * 16;
            const float* p = in + ((size_t)b * 64 + ci) * NPOS + h * 64 + w0;
#pragma unroll
            for (int j = 0; j < 16; j += 4) {
                float4 v = *(const float4*)(p + j);
                t[ci][w0 + j] = v.x; t[ci][w0 + j + 1] = v.y;
                t[ci][w0 + j + 2] = v.z; t[ci][w0 + j + 3] = v.w;
            }
        }
        __syncthreads();
        const int w = tt >> 2, c0 = (tt & 3) * 16;
        unsigned short us[16];
#pragma unroll
        for (int j = 0; j < 16; ++j) us[j] = f2bf(t[c0 + j][w]);
        unsigned short* q = out + ((size_t)b * PADN + (h + 1) * PADW + (w + 1)) * CD + c0;
        *(uint4*)q = *(uint4*)us;
        *(uint4*)(q + 8) = *(uint4*)(us + 8);
    }
}

// ---------------------------------------------------------------------------
// Implicit-GEMM conv3x3 via MFMA — WEIGHT-STATIONARY version.
// Block = 4 h rows x 64 pos x 32 co; 4 waves, wave wv owns pos quarter wv*16
// across all 4 rows. ALL 36 weight slots (18 frags x 2 cc, 36 KB) staged in
// LDS once per src; then 4 rows x 36 MFMAs/wave with NO further barriers.
// grid (16 hgroup, NB, 2*nconv): z>>1 = conv (+base), z&1 = co half.
// D mapping: co = (ch*2+cc)*16 + l15, pos = wv*16 + 4g + r.
// layouts: 0 = bf16 [n][co], 1 = bf16 [co][n], 2 = fp32 [co][n] (d_out)
// K-producing convs (1,3) get bias x log2(e) (weights already scaled).
// ---------------------------------------------------------------------------
__global__ __launch_bounds__(256) void conv_mfma_kernel(
    const unsigned short* __restrict__ xpad, const unsigned short* __restrict__ ypad,
    const unsigned short* __restrict__ rpadR, const unsigned short* __restrict__ rpadI,
    const unsigned short* __restrict__ Wf,
    const float* __restrict__ qb, const float* __restrict__ rkb,
    const float* __restrict__ rvb, const float* __restrict__ ikb,
    const float* __restrict__ ivb, const float* __restrict__ srb,
    unsigned short* __restrict__ Qt, unsigned short* __restrict__ KtR,
    unsigned short* __restrict__ VR, unsigned short* __restrict__ KtI,
    unsigned short* __restrict__ VI, float* __restrict__ outf,
    int convid_base)
{
    const int conv = convid_base + (blockIdx.z >> 1);
    const int ch   = blockIdx.z & 1;            // co half
    const int hg = blockIdx.x, b = blockIdx.y;
    const unsigned short *in0, *in1; const float* bias;
    int nsrc, wfbase, layout; void* outp;
    switch (conv) {
        case 0:  in0 = xpad;  in1 = ypad;  nsrc = 2; wfbase = 0;   bias = qb;  outp = Qt;  layout = 0; break;
        case 1:  in0 = xpad;  in1 = 0;     nsrc = 1; wfbase = 36;  bias = rkb; outp = KtR; layout = 0; break;
        case 2:  in0 = xpad;  in1 = 0;     nsrc = 1; wfbase = 54;  bias = rvb; outp = VR;  layout = 1; break;
        case 3:  in0 = ypad;  in1 = 0;     nsrc = 1; wfbase = 72;  bias = ikb; outp = KtI; layout = 0; break;
        case 4:  in0 = ypad;  in1 = 0;     nsrc = 1; wfbase = 90;  bias = ivb; outp = VI;  layout = 1; break;
        default: in0 = rpadR; in1 = rpadI; nsrc = 2; wfbase = 108; bias = srb; outp = outf; layout = 2; break;
    }
    const float bmul = (conv == 1 || conv == 3) ? LOG2E : 1.0f;
    const int lane = threadIdx.x & 63, wv = threadIdx.x >> 6;
    const int l15 = lane & 15, g = lane >> 4;

    __shared__ unsigned short Wl[36 * 512];     // 36 slots x 1KB = 36 KB

    f32x4_t acc[4][2];                          // [row][cc]
#pragma unroll
    for (int i = 0; i < 4; ++i)
#pragma unroll
        for (int j = 0; j < 2; ++j) acc[i][j] = (f32x4_t){0.f, 0.f, 0.f, 0.f};

    for (int src = 0; src < nsrc; ++src) {
        if (src) __syncthreads();               // readers of prev weights done
        // ---- stage all 36 weight slots (wave wv: slots 9wv..9wv+8) ----
#pragma unroll
        for (int j = 0; j < 9; ++j) {
            const int slot = wv * 9 + j;
            const int fg = wfbase + src * 18 + (slot >> 1);
            gload_lds16(Wf + ((size_t)(fg * 4 + ch * 2 + (slot & 1)) * 64 + lane) * 8,
                        Wl + slot * 512);
        }
        __syncthreads();                        // stage visible (vmcnt drained)
        const unsigned short* base = (src ? in1 : in0) + (size_t)b * PADN * CD;
#pragma unroll
        for (int r = 0; r < 4; ++r) {
            const int hrow = hg * 4 + r;
#pragma unroll
            for (int ky = 0; ky < 3; ++ky) {
#pragma unroll
                for (int kx = 0; kx < 3; ++kx) {
                    const int pos = (hrow + ky) * PADW + wv * 16 + kx + l15;
                    const unsigned short* ap = base + (size_t)pos * CD + g * 8;
#pragma unroll
                    for (int kt = 0; kt < 2; ++kt) {
                        bf16x8_t a = *(const bf16x8_t*)(ap + kt * 32);
                        const int fl = (ky * 3 + kx) * 2 + kt;
#pragma unroll
                        for (int cc = 0; cc < 2; ++cc) {
                            bf16x8_t bfr = *(const bf16x8_t*)(Wl + (size_t)(fl * 2 + cc) * 512 + lane * 8);
                            acc[r][cc] = __builtin_amdgcn_mfma_f32_16x16x32_bf16(a, bfr, acc[r][cc], 0, 0, 0);
                        }
                    }
                }
            }
        }
    }

#pragma unroll
    for (int r = 0; r < 4; ++r) {
        const int nb4 = (hg * 4 + r) * 64 + wv * 16 + g * 4;
        if (layout == 0) {
            unsigned short* o = (unsigned short*)outp + (size_t)b * NPOS * CD;
#pragma unroll
            for (int cc = 0; cc < 2; ++cc) {
                const int co = (ch * 2 + cc) * 16 + l15;
                const float bv = bias[co] * bmul;
#pragma unroll
                for (int rr = 0; rr < 4; ++rr)
                    o[(size_t)(nb4 + rr) * CD + co] = f2bf(fmaxf(acc[r][cc][rr] + bv, 0.f));
            }
        } else if (layout == 1) {
            unsigned short* o = (unsigned short*)outp + (size_t)b * CD * NPOS;
#pragma unroll
            for (int cc = 0; cc < 2; ++cc) {
                const int cch = (ch * 2 + cc) * 16 + l15;
                const float bv = bias[cch];
                unsigned short us[4];
#pragma unroll
                for (int rr = 0; rr < 4; ++rr) us[rr] = f2bf(fmaxf(acc[r][cc][rr] + bv, 0.f));
                *(uint2*)(o + (size_t)cch * NPOS + nb4) = *(uint2*)us;
            }
        } else {
            float* o = (float*)outp + (size_t)b * CD * NPOS;
#pragma unroll
            for (int cc = 0; cc < 2; ++cc) {
                const int cch = (ch * 2 + cc) * 16 + l15;
                const float bv = bias[cch];
                f32x4_t v;
#pragma unroll
                for (int rr = 0; rr < 4; ++rr) v[rr] = fmaxf(acc[r][cc][rr] + bv, 0.f);
                *(f32x4_t*)(o + (size_t)cch * NPOS + nb4) = v;
            }
        }
    }
}

// ---------------------------------------------------------------------------
// Flash attention over an n-segment (base-2 softmax, defer-max, VALU-lean).
//   Qt/Kt bf16 [b][n][64]; V bf16 [b][c][n]. K pre-scaled by log2(e).
// 2048 blocks: fid&1=att, (fid>>1)&3=b (fid&7 = XCD group), (fid>>3)&3=seg,
// mblk=fid>>5. block 256 = 4 waves x 16 m rows.
// Q A-frags DIRECT FROM GLOBAL (identical across the 4 waves -> L1-served;
// removes 16KB LDS + half the LDS-pipe traffic). V double-buffered in LDS
// via global_load_lds (XOR chunk swizzle on the GLOBAL source; linear LDS
// dest; same XOR on reads). ONE __syncthreads/iter; stage(next) after it.
// LDS 25088 B -> 6 blocks/CU.
// Opart fp32 [att][b][seg][m][c]; ml fp32 [att][b][seg][m][2] (base-2 m, l).
// ---------------------------------------------------------------------------
__global__ __launch_bounds__(256) void attn_kernel(
    const unsigned short* __restrict__ Qt,
    const unsigned short* __restrict__ KtR, const unsigned short* __restrict__ KtI,
    const unsigned short* __restrict__ VR,  const unsigned short* __restrict__ VI,
    float* __restrict__ Opart, float* __restrict__ ml)
{
    const int fid = blockIdx.x;
    const int att = fid & 1;
    const int b   = (fid >> 1) & 3;
    const int seg = (fid >> 3) & 3;
    const int mblk = fid >> 5;
    const int lane = threadIdx.x & 63, wv = threadIdx.x >> 6;
    const int l15 = lane & 15, g = lane >> 4;
    const int m0 = mblk * 64 + wv * 16;

    const unsigned short* Qb = Qt + (size_t)b * NPOS * CD;
    const unsigned short* Kb = (att ? KtI : KtR) + (size_t)b * NPOS * CD;
    const unsigned short* Vb = (att ? VI : VR) + (size_t)b * CD * NPOS;

    __shared__ unsigned short Vs[2][64 * 64];
    __shared__ unsigned short plds[4][16 * 68];
    unsigned short* pl = plds[wv];

    const bf16x8_t bK0 = *(const bf16x8_t*)&Kb[(size_t)(m0 + l15) * CD + g * 8];
    const bf16x8_t bK1 = *(const bf16x8_t*)&Kb[(size_t)(m0 + l15) * CD + 32 + g * 8];

    f32x4_t O[4];
#pragma unroll
    for (int i = 0; i < 4; ++i) O[i] = (f32x4_t){0.f, 0.f, 0.f, 0.f};
    float mrun = -3.0e38f, lsum = 0.f;   // per-lane partials

    const int csw = (lane & 7) ^ ((lane >> 3) & 7);   // swizzled source chunk
    const int sx = l15 & 7;                            // read-side XOR key
    const int nbase = seg * (NPOS / NSEG);

    // hoisted V staging pointers (per-thread global src, wave-uniform dest)
    const int rq = wv * 16 + (lane >> 3);
    const unsigned short* vsrc0 = Vb + (size_t)rq * NPOS + nbase + csw * 8;
    const unsigned short* vsrc1 = vsrc0 + (size_t)8 * NPOS;
    unsigned short* vdst = &Vs[0][(wv * 16) * 64];

#define STAGE_V(buf, itv) do {                                                \
        const size_t vo = (size_t)(itv) * 64;                                 \
        gload_lds16(vsrc0 + vo, vdst + (buf) * 4096);                         \
        gload_lds16(vsrc1 + vo, vdst + (buf) * 4096 + 512);                   \
    } while (0)

    STAGE_V(0, 0);

    const unsigned short* qrow = Qb + (size_t)(nbase + l15) * CD + g * 8;

    for (int it = 0; it < NT; ++it) {
        const int cur = it & 1;
        __syncthreads();   // drains stage(cur) DMAs; prev-iter reads done
        if (it + 1 < NT) STAGE_V(cur ^ 1, it + 1);   // overlaps compute below

        // ---- QK^T: St[row=n_local, col=m]; Q direct from global (L1) ----
        const unsigned short* qp = qrow + (size_t)it * 64 * CD;
        f32x4_t St[4];
        __builtin_amdgcn_s_setprio(1);
#pragma unroll
        for (int nt = 0; nt < 4; ++nt) {
            bf16x8_t a0 = *(const bf16x8_t*)(qp + (size_t)(nt * 16) * CD);
            bf16x8_t a1 = *(const bf16x8_t*)(qp + (size_t)(nt * 16) * CD + 32);
            f32x4_t c = (f32x4_t){0.f, 0.f, 0.f, 0.f};
            c = __builtin_amdgcn_mfma_f32_16x16x32_bf16(a0, bK0, c, 0, 0, 0);
            c = __builtin_amdgcn_mfma_f32_16x16x32_bf16(a1, bK1, c, 0, 0, 0);
            St[nt] = c;
        }
        __builtin_amdgcn_s_setprio(0);

        // ---- online softmax, base-2, defer-max; max3-shaped chains ----
        float tmax = St[0][0];
#pragma unroll
        for (int nt = 0; nt < 4; ++nt) {
            tmax = fmaxf(fmaxf(tmax, St[nt][0]), St[nt][1]);   // -> v_max3
            tmax = fmaxf(fmaxf(tmax, St[nt][2]), St[nt][3]);
        }
        if (!__all(tmax <= mrun + 12.0f)) {
            float tr = fmaxf(tmax, __shfl_xor(tmax, 16));
            tr = fmaxf(tr, __shfl_xor(tr, 32));
            const float mnew = fmaxf(mrun, tr);
            const float corr = __builtin_amdgcn_exp2f(mrun - mnew);
            lsum *= corr;
#pragma unroll
            for (int i = 0; i < 4; ++i) {
                O[i][0] *= corr; O[i][1] *= corr; O[i][2] *= corr; O[i][3] *= corr;
            }
            mrun = mnew;
        }
        unsigned int pw[8];
#pragma unroll
        for (int nt = 0; nt < 4; ++nt) {
            float p0 = __builtin_amdgcn_exp2f(St[nt][0] - mrun);
            float p1 = __builtin_amdgcn_exp2f(St[nt][1] - mrun);
            float p2 = __builtin_amdgcn_exp2f(St[nt][2] - mrun);
            float p3 = __builtin_amdgcn_exp2f(St[nt][3] - mrun);
            lsum += (p0 + p1) + (p2 + p3);
            pw[nt * 2 + 0] = cvtpk_bf16(p0, p1);
            pw[nt * 2 + 1] = cvtpk_bf16(p2, p3);
        }
        // ---- P -> per-wave LDS ----
#pragma unroll
        for (int nt = 0; nt < 4; ++nt)
            *(uint2*)&pl[l15 * 68 + nt * 16 + g * 4] =
                make_uint2(pw[nt * 2], pw[nt * 2 + 1]);

        // ---- PV: O[c,m] += V[c,:] P[m,:] ----
        __builtin_amdgcn_s_setprio(1);
#pragma unroll
        for (int nc = 0; nc < 2; ++nc) {
            union { bf16x8_t v; uint2 d2[2]; } bp;
            bp.d2[0] = *(uint2*)&pl[l15 * 68 + nc * 32 + g * 8];
            bp.d2[1] = *(uint2*)&pl[l15 * 68 + nc * 32 + g * 8 + 4];
#pragma unroll
            for (int ct = 0; ct < 4; ++ct) {
                bf16x8_t av = *(const bf16x8_t*)
                    (&Vs[cur][(ct * 16 + l15) * 64 + (((nc * 4 + g) ^ sx) * 8)]);
                O[ct] = __builtin_amdgcn_mfma_f32_16x16x32_bf16(av, bp.v, O[ct], 0, 0, 0);
            }
        }
        __builtin_amdgcn_s_setprio(0);
    }

    // ---- epilogue: reduce lsum across g, write partials ----
    float lred = lsum + __shfl_xor(lsum, 16);
    lred += __shfl_xor(lred, 32);
    float* Ob = Opart + ((((size_t)att * NB + b) * NSEG + seg) * NPOS) * CD;
    const int m = m0 + l15;
#pragma unroll
    for (int ct = 0; ct < 4; ++ct)
        *(f32x4_t*)(Ob + (size_t)m * CD + ct * 16 + g * 4) = O[ct];
    if (g == 0) {
        float* mlb = ml + ((((size_t)att * NB + b) * NSEG + seg) * NPOS + m) * 2;
        mlb[0] = mrun; mlb[1] = lred;
    }
#undef STAGE_V
}

// ---------------------------------------------------------------------------
// Combine NSEG partials -> refine = gamma*O/L + resid, bf16 into padded
// layout for the SR conv. grid (256 mtile16, NB, 2 att). Base-2 weights.
// ---------------------------------------------------------------------------
__global__ __launch_bounds__(256) void combine_kernel(
    const float* __restrict__ Opart, const float* __restrict__ ml,
    const float* __restrict__ x, const float* __restrict__ y,
    const float* __restrict__ g1, const float* __restrict__ g2,
    unsigned short* __restrict__ rpadR, unsigned short* __restrict__ rpadI)
{
    const int mt = blockIdx.x, b = blockIdx.y, att = blockIdx.z;
    const float* resid = att ? x : y;
    const float gamma = att ? g2[0] : g1[0];
    unsigned short* rp = (att ? rpadI : rpadR) + (size_t)b * PADN * CD;
    __shared__ float t[64][17];
    const int tt = threadIdx.x;
    {
        const int c = tt >> 2, m4 = (tt & 3) * 4;
        const float4 v = *(const float4*)(resid + ((size_t)b * CD + c) * NPOS + mt * 16 + m4);
        t[c][m4] = v.x; t[c][m4 + 1] = v.y; t[c][m4 + 2] = v.z; t[c][m4 + 3] = v.w;
    }
    __syncthreads();
    const int c = tt & 63, mq = tt >> 6;
    const size_t ob = (((size_t)att * NB + b) * NSEG) * NPOS * CD;
    const size_t mb = (((size_t)att * NB + b) * NSEG) * NPOS;
#pragma unroll
    for (int p = 0; p < 4; ++p) {
        const int mloc = mq * 4 + p;
        const int m = mt * 16 + mloc;
        float mm[NSEG], llv[NSEG];
#pragma unroll
        for (int s = 0; s < NSEG; ++s) {
            mm[s] = ml[(mb + (size_t)s * NPOS + m) * 2];
            llv[s] = ml[(mb + (size_t)s * NPOS + m) * 2 + 1];
        }
        float M = mm[0];
#pragma unroll
        for (int s = 1; s < NSEG; ++s) M = fmaxf(M, mm[s]);
        float Ov = 0.f, L = 0.f;
#pragma unroll
        for (int s = 0; s < NSEG; ++s) {
            const float wgt = __ocml_exp2_f32(mm[s] - M);
            L += wgt * llv[s];
            Ov += wgt * Opart[ob + ((size_t)s * NPOS + m) * CD + c];
        }
        const float val = fmaf(gamma, Ov / L, t[c][mloc]);
        const int h = m >> 6, w_ = m & 63;
        rp[((size_t)((h + 1) * PADW) + (w_ + 1)) * CD + c] = f2bf(val);
    }
}

// ---------------------------------------------------------------------------
extern "C" void kernel_launch(void* const* d_in, const int* in_sizes, int n_in,
                              void* d_out, int out_size, void* d_ws, size_t ws_size,
                              hipStream_t stream)
{
    const float* x    = (const float*)d_in[0];
    const float* y    = (const float*)d_in[1];
    const float* q_w  = (const float*)d_in[2];
    const float* q_s  = (const float*)d_in[3];
    const float* q_b  = (const float*)d_in[4];
    const float* rk_w = (const float*)d_in[5];
    const float* rk_s = (const float*)d_in[6];
    const float* rk_b = (const float*)d_in[7];
    const float* rv_w = (const float*)d_in[8];
    const float* rv_s = (const float*)d_in[9];
    const float* rv_b = (const float*)d_in[10];
    const float* ik_w = (const float*)d_in[11];
    const float* ik_s = (const float*)d_in[12];
    const float* ik_b = (const float*)d_in[13];
    const float* iv_w = (const float*)d_in[14];
    const float* iv_s = (const float*)d_in[15];
    const float* iv_b = (const float*)d_in[16];
    const float* sr_w = (const float*)d_in[17];
    const float* sr_s = (const float*)d_in[18];
    const float* sr_b = (const float*)d_in[19];
    const float* g1   = (const float*)d_in[20];
    const float* g2   = (const float*)d_in[21];

    char* ws = (char*)d_ws;
    size_t off = 0;
    auto alloc = [&](size_t bytes) {
        void* p = ws + off; off += (bytes + 255) & ~(size_t)255; return p;
    };
    const size_t PADB = (size_t)NB * PADN * CD * 2;
    unsigned short* xpad  = (unsigned short*)alloc(PADB);
    unsigned short* ypad  = (unsigned short*)alloc(PADB);
    unsigned short* rpadR = (unsigned short*)alloc(PADB);
    unsigned short* rpadI = (unsigned short*)alloc(PADB);
    unsigned short* Qt  = (unsigned short*)alloc((size_t)NB * NPOS * CD * 2);
    unsigned short* KtR = (unsigned short*)alloc((size_t)NB * NPOS * CD * 2);
    unsigned short* KtI = (unsigned short*)alloc((size_t)NB * NPOS * CD * 2);
    unsigned short* VR  = (unsigned short*)alloc((size_t)NB * NPOS * CD * 2);
    unsigned short* VI  = (unsigned short*)alloc((size_t)NB * NPOS * CD * 2);
    unsigned short* Wf  = (unsigned short*)alloc((size_t)144 * 4 * 64 * 16);
    float* Opart = (float*)alloc((size_t)2 * NB * NSEG * NPOS * CD * 4);
    float* mlb   = (float*)alloc((size_t)2 * NB * NSEG * NPOS * 2 * 4);

    // prep: halo-zero + weight repack + input pack (one launch, no memset)
    prep_kernel<<<dim3(672), 256, 0, stream>>>(
        x, y, q_w, rk_w, rv_w, ik_w, iv_w, sr_w,
        q_s, rk_s, rv_s, ik_s, iv_s, sr_s, xpad, Wf);
    // 5 pre-attention convs, weight-stationary 4-row blocks, co-split
    conv_mfma_kernel<<<dim3(16, NB, 10), 256, 0, stream>>>(
        xpad, ypad, rpadR, rpadI, Wf,
        q_b, rk_b, rv_b, ik_b, iv_b, sr_b,
        Qt, KtR, VR, KtI, VI, nullptr, 0);
    // 64 mblk x 4 b x 2 att x 4 seg = 2048 blocks
    attn_kernel<<<dim3(64 * NB * 2 * NSEG), 256, 0, stream>>>(
        Qt, KtR, KtI, VR, VI, Opart, mlb);
    combine_kernel<<<dim3(256, NB, 2), 256, 0, stream>>>(
        Opart, mlb, x, y, g1, g2, rpadR, rpadI);
    // final SR conv -> d_out fp32 NCHW (weight-stationary, co-split)
    conv_mfma_kernel<<<dim3(16, NB, 2), 256, 0, stream>>>(
        xpad, ypad, rpadR, rpadI, Wf,
        q_b, rk_b, rv_b, ik_b, iv_b, sr_b,
        Qt, KtR, VR, KtI, VI, (float*)d_out, 5);
}

// Round 8
// 207.379 us; speedup vs baseline: 1.3152x; 1.3152x over previous
//
#include <hip/hip_runtime.h>
#include <hip/hip_bf16.h>

#define NPOS 4096          // 64*64 positions
#define CD   64            // channels
#define NB   4             // batch
#define PADW 66
#define PADN (66*66)       // padded positions (zero halo)
#define NSEG 4             // attention n-split
#define NT   (NPOS / NSEG / 64)
#define LOG2E 1.4426950408889634f

extern "C" __device__ float __ocml_exp2_f32(float);

typedef __bf16 bf16x8_t __attribute__((ext_vector_type(8)));
typedef float  f32x4_t  __attribute__((ext_vector_type(4)));

static __device__ __forceinline__ unsigned short f2bf(float f) {
    return __builtin_bit_cast(unsigned short, __float2bfloat16(f));
}

static __device__ __forceinline__ void gload_lds16(const void* g, void* l) {
    __builtin_amdgcn_global_load_lds(
        (const __attribute__((address_space(1))) void*)g,
        (__attribute__((address_space(3))) void*)l, 16, 0, 0);
}

static __device__ __forceinline__ unsigned cvtpk_bf16(float lo, float hi) {
    unsigned r;
    asm("v_cvt_pk_bf16_f32 %0, %1, %2" : "=v"(r) : "v"(lo), "v"(hi));
    return r;
}

// ---------------------------------------------------------------------------
// prep: fused {halo-zero, weight-repack, input-pack} in one launch.
// grid 672 = 16 halo + 144 wrepack + 512 pack. block 256.
// ---------------------------------------------------------------------------
__global__ __launch_bounds__(256) void prep_kernel(
    const float* __restrict__ x, const float* __restrict__ y,
    const float* __restrict__ qw, const float* __restrict__ rkw,
    const float* __restrict__ rvw, const float* __restrict__ ikw,
    const float* __restrict__ ivw, const float* __restrict__ srw,
    const float* __restrict__ qs, const float* __restrict__ rks,
    const float* __restrict__ rvs, const float* __restrict__ iks,
    const float* __restrict__ ivs, const float* __restrict__ srs,
    unsigned short* __restrict__ pads, unsigned short* __restrict__ Wf)
{
    const int bx = blockIdx.x;
    if (bx < 16) {
        unsigned short* p = pads + (size_t)bx * PADN * CD;
        const uint4 z = make_uint4(0, 0, 0, 0);
        for (int idx = threadIdx.x; idx < 260 * 8; idx += 256) {
            const int pi = idx >> 3, chn = idx & 7;
            int pos;
            if (pi < 66)       pos = pi;
            else if (pi < 132) pos = 65 * PADW + (pi - 66);
            else { const int rem = pi - 132;
                   pos = (1 + (rem >> 1)) * PADW + ((rem & 1) ? 65 : 0); }
            *(uint4*)(p + (size_t)pos * CD + chn * 8) = z;
        }
        return;
    }
    if (bx < 160) {
        const int f = bx - 16;
        const float* w; const float* s; int cin, local;
        if (f < 36)       { w = qw;  s = qs;  cin = 128; local = f; }
        else if (f < 54)  { w = rkw; s = rks; cin = 64;  local = f - 36; }
        else if (f < 72)  { w = rvw; s = rvs; cin = 64;  local = f - 54; }
        else if (f < 90)  { w = ikw; s = iks; cin = 64;  local = f - 72; }
        else if (f < 108) { w = ivw; s = ivs; cin = 64;  local = f - 90; }
        else              { w = srw; s = srs; cin = 128; local = f - 108; }
        const int src = (cin == 128) ? local / 18 : 0;
        const int rem = (cin == 128) ? local % 18 : local;
        const int tap = rem >> 1, kt = rem & 1;
        const int t = threadIdx.x, cot = t >> 6, l = t & 63;
        const int co = cot * 16 + (l & 15);
        const float kmul = ((f >= 36 && f < 54) || (f >= 72 && f < 90)) ? LOG2E : 1.0f;
        const float sc = s[co] * kmul;
        unsigned short us[8];
#pragma unroll
        for (int e = 0; e < 8; ++e) {
            const int ci = src * 64 + kt * 32 + ((l >> 4) * 8) + e;
            us[e] = f2bf(w[((size_t)co * cin + ci) * 9 + tap] * sc);
        }
        *(uint4*)(Wf + ((size_t)(f * 4 + cot) * 64 + l) * 8) = *(uint4*)us;
        return;
    }
    {
        const int idx = bx - 160;
        const int h = idx & 63, b = (idx >> 6) & 3, src = idx >> 8;
        const float* in = src ? y : x;
        unsigned short* out = pads + (size_t)src * NB * PADN * CD;
        __shared__ float t[64][65];
        const int tt = threadIdx.x;
        {
            const int ci = tt >> 2, w0 = (tt & 3) * 16;
            const float* p = in + ((size_t)b * 64 + ci) * NPOS + h * 64 + w0;
#pragma unroll
            for (int j = 0; j < 16; j += 4) {
                float4 v = *(const float4*)(p + j);
                t[ci][w0 + j] = v.x; t[ci][w0 + j + 1] = v.y;
                t[ci][w0 + j + 2] = v.z; t[ci][w0 + j + 3] = v.w;
            }
        }
        __syncthreads();
        const int w = tt >> 2, c0 = (tt & 3) * 16;
        unsigned short us[16];
#pragma unroll
        for (int j = 0; j < 16; ++j) us[j] = f2bf(t[c0 + j][w]);
        unsigned short* q = out + ((size_t)b * PADN + (h + 1) * PADW + (w + 1)) * CD + c0;
        *(uint4*)q = *(uint4*)us;
        *(uint4*)(q + 8) = *(uint4*)(us + 8);
    }
}

// ---------------------------------------------------------------------------
// Implicit-GEMM conv3x3 via MFMA — A-tile AND weights in LDS.
// Block = 2 h rows x 64 pos x 32 co (co-half); 4 waves: wave wv -> row
// rr=wv>>1, pos-seg (wv&1)*32, 2 pos16-frags x 2 cot.
// Per src: stage contiguous 4-row A-tile (264 pos x 128B = 33.8KB) via
// global_load_lds with SOURCE-side XOR chunk swizzle (s = idx with low-3
// bits ^ row-bits; involution) so ds_read_b128 at 128B lane stride is
// conflict-free; stage all 36 W slots (36KB); ONE barrier; then 72
// ds_reads : 72 MFMAs per wave. LDS 70.7KB -> 2 blocks/CU.
// grid (32 rowpair, NB, 2*nconv): z>>1 = conv (+base), z&1 = co half.
// D mapping: co = (ch*2+cc)*16 + l15, pos = wseg + pf*16 + 4g + r.
// layouts: 0 = bf16 [n][co], 1 = bf16 [co][n], 2 = fp32 [co][n] (d_out)
// K-producing convs (1,3) get bias x log2(e) (weights already scaled).
// ---------------------------------------------------------------------------
__global__ __launch_bounds__(256) void conv_mfma_kernel(
    const unsigned short* __restrict__ xpad, const unsigned short* __restrict__ ypad,
    const unsigned short* __restrict__ rpadR, const unsigned short* __restrict__ rpadI,
    const unsigned short* __restrict__ Wf,
    const float* __restrict__ qb, const float* __restrict__ rkb,
    const float* __restrict__ rvb, const float* __restrict__ ikb,
    const float* __restrict__ ivb, const float* __restrict__ srb,
    unsigned short* __restrict__ Qt, unsigned short* __restrict__ KtR,
    unsigned short* __restrict__ VR, unsigned short* __restrict__ KtI,
    unsigned short* __restrict__ VI, float* __restrict__ outf,
    int convid_base)
{
    const int conv = convid_base + (blockIdx.z >> 1);
    const int ch   = blockIdx.z & 1;            // co half
    const int hg = blockIdx.x, b = blockIdx.y;
    const unsigned short *in0, *in1; const float* bias;
    int nsrc, wfbase, layout; void* outp;
    switch (conv) {
        case 0:  in0 = xpad;  in1 = ypad;  nsrc = 2; wfbase = 0;   bias = qb;  outp = Qt;  layout = 0; break;
        case 1:  in0 = xpad;  in1 = 0;     nsrc = 1; wfbase = 36;  bias = rkb; outp = KtR; layout = 0; break;
        case 2:  in0 = xpad;  in1 = 0;     nsrc = 1; wfbase = 54;  bias = rvb; outp = VR;  layout = 1; break;
        case 3:  in0 = ypad;  in1 = 0;     nsrc = 1; wfbase = 72;  bias = ikb; outp = KtI; layout = 0; break;
        case 4:  in0 = ypad;  in1 = 0;     nsrc = 1; wfbase = 90;  bias = ivb; outp = VI;  layout = 1; break;
        default: in0 = rpadR; in1 = rpadI; nsrc = 2; wfbase = 108; bias = srb; outp = outf; layout = 2; break;
    }
    const float bmul = (conv == 1 || conv == 3) ? LOG2E : 1.0f;
    const int tid = threadIdx.x;
    const int lane = tid & 63, wv = tid >> 6;
    const int l15 = lane & 15, g = lane >> 4;
    const int rr = wv >> 1;                     // wave's output row (0/1)
    const int wseg = (wv & 1) * 32;             // wave's pos segment

    __shared__ unsigned short As[264 * 64];     // 4 rows x 66 pos x 64c = 33.8KB
    __shared__ unsigned short Wl[36 * 512];     // 36 slots x 1KB = 36KB

    f32x4_t acc[2][2];                          // [pf][cc]
#pragma unroll
    for (int i = 0; i < 2; ++i)
#pragma unroll
        for (int j = 0; j < 2; ++j) acc[i][j] = (f32x4_t){0.f, 0.f, 0.f, 0.f};

    for (int src = 0; src < nsrc; ++src) {
        if (src) __syncthreads();               // readers of prev src done
        // ---- stage A-tile: 2112 16B chunks, source-side XOR swizzle ----
        const unsigned short* tsrc =
            (src ? in1 : in0) + ((size_t)b * PADN + (size_t)hg * 2 * PADW) * CD;
        for (int k = 0; k < 2112; k += 256) {
            const int idx = k + tid;
            if (idx < 2112) {                   // wave-uniform tail
                const int s = (idx & ~7) | ((idx ^ (idx >> 3)) & 7);
                gload_lds16(tsrc + (size_t)s * 8, As + (size_t)(idx & ~63) * 8);
            }
        }
        // ---- stage W: wave wv slots 9wv..9wv+8 ----
#pragma unroll
        for (int j = 0; j < 9; ++j) {
            const int slot = wv * 9 + j;
            const int fg = wfbase + src * 18 + (slot >> 1);
            gload_lds16(Wf + ((size_t)(fg * 4 + ch * 2 + (slot & 1)) * 64 + lane) * 8,
                        Wl + slot * 512);
        }
        __syncthreads();                        // stage visible (vmcnt drained)
        // ---- compute: 18 tap-kt x {2 A ds_reads, 2 W ds_reads, 4 MFMA} ----
#pragma unroll
        for (int ky = 0; ky < 3; ++ky) {
#pragma unroll
            for (int kx = 0; kx < 3; ++kx) {
#pragma unroll
                for (int kt = 0; kt < 2; ++kt) {
                    const int fj = (ky * 3 + kx) * 2 + kt;
                    bf16x8_t a[2];
#pragma unroll
                    for (int pf = 0; pf < 2; ++pf) {
                        const int P = (rr + ky) * 66 + wseg + pf * 16 + kx + l15;
                        const int q = (kt * 4 + g) ^ (P & 7);
                        a[pf] = *(const bf16x8_t*)(As + P * 64 + q * 8);
                    }
#pragma unroll
                    for (int cc = 0; cc < 2; ++cc) {
                        bf16x8_t wfr = *(const bf16x8_t*)(Wl + (size_t)(fj * 2 + cc) * 512 + lane * 8);
                        acc[0][cc] = __builtin_amdgcn_mfma_f32_16x16x32_bf16(a[0], wfr, acc[0][cc], 0, 0, 0);
                        acc[1][cc] = __builtin_amdgcn_mfma_f32_16x16x32_bf16(a[1], wfr, acc[1][cc], 0, 0, 0);
                    }
                }
            }
        }
    }

    const int hrow = hg * 2 + rr;
#pragma unroll
    for (int pf = 0; pf < 2; ++pf) {
        const int nb4 = hrow * 64 + wseg + pf * 16 + g * 4;
        if (layout == 0) {
            unsigned short* o = (unsigned short*)outp + (size_t)b * NPOS * CD;
#pragma unroll
            for (int cc = 0; cc < 2; ++cc) {
                const int co = (ch * 2 + cc) * 16 + l15;
                const float bv = bias[co] * bmul;
#pragma unroll
                for (int r = 0; r < 4; ++r)
                    o[(size_t)(nb4 + r) * CD + co] = f2bf(fmaxf(acc[pf][cc][r] + bv, 0.f));
            }
        } else if (layout == 1) {
            unsigned short* o = (unsigned short*)outp + (size_t)b * CD * NPOS;
#pragma unroll
            for (int cc = 0; cc < 2; ++cc) {
                const int cch = (ch * 2 + cc) * 16 + l15;
                const float bv = bias[cch];
                unsigned short us[4];
#pragma unroll
                for (int r = 0; r < 4; ++r) us[r] = f2bf(fmaxf(acc[pf][cc][r] + bv, 0.f));
                *(uint2*)(o + (size_t)cch * NPOS + nb4) = *(uint2*)us;
            }
        } else {
            float* o = (float*)outp + (size_t)b * CD * NPOS;
#pragma unroll
            for (int cc = 0; cc < 2; ++cc) {
                const int cch = (ch * 2 + cc) * 16 + l15;
                const float bv = bias[cch];
                f32x4_t v;
#pragma unroll
                for (int r = 0; r < 4; ++r) v[r] = fmaxf(acc[pf][cc][r] + bv, 0.f);
                *(f32x4_t*)(o + (size_t)cch * NPOS + nb4) = v;
            }
        }
    }
}

// ---------------------------------------------------------------------------
// Flash attention — r6 version verbatim (73.5 us measured).
// Qt/Kt bf16 [b][n][64]; V bf16 [b][c][n]. K pre-scaled by log2(e).
// 2048 blocks: fid&1=att, (fid>>1)&3=b (fid&7 = XCD group), (fid>>3)&3=seg,
// mblk=fid>>5. block 256 = 4 waves x 16 m rows.
// Q+V double-buffered in LDS via global_load_lds (XOR chunk swizzle on the
// GLOBAL source; linear LDS dest; same XOR on reads). ONE __syncthreads/iter;
// stage(next) issued right after it. cvt_pk_bf16 packing, exp2f, max3 chains.
// Opart fp32 [att][b][seg][m][c]; ml fp32 [att][b][seg][m][2] (base-2 m, l).
// ---------------------------------------------------------------------------
__global__ __launch_bounds__(256) void attn_kernel(
    const unsigned short* __restrict__ Qt,
    const unsigned short* __restrict__ KtR, const unsigned short* __restrict__ KtI,
    const unsigned short* __restrict__ VR,  const unsigned short* __restrict__ VI,
    float* __restrict__ Opart, float* __restrict__ ml)
{
    const int fid = blockIdx.x;
    const int att = fid & 1;
    const int b   = (fid >> 1) & 3;
    const int seg = (fid >> 3) & 3;
    const int mblk = fid >> 5;
    const int lane = threadIdx.x & 63, wv = threadIdx.x >> 6;
    const int l15 = lane & 15, g = lane >> 4;
    const int m0 = mblk * 64 + wv * 16;

    const unsigned short* Qb = Qt + (size_t)b * NPOS * CD;
    const unsigned short* Kb = (att ? KtI : KtR) + (size_t)b * NPOS * CD;
    const unsigned short* Vb = (att ? VI : VR) + (size_t)b * CD * NPOS;

    __shared__ unsigned short Qs[2][64 * 64];
    __shared__ unsigned short Vs[2][64 * 64];
    __shared__ unsigned short plds[4][16 * 68];
    unsigned short* pl = plds[wv];

    const bf16x8_t bK0 = *(const bf16x8_t*)&Kb[(size_t)(m0 + l15) * CD + g * 8];
    const bf16x8_t bK1 = *(const bf16x8_t*)&Kb[(size_t)(m0 + l15) * CD + 32 + g * 8];

    f32x4_t O[4];
#pragma unroll
    for (int i = 0; i < 4; ++i) O[i] = (f32x4_t){0.f, 0.f, 0.f, 0.f};
    float mrun = -3.0e38f, lsum = 0.f;   // per-lane partials

    const int csw = (lane & 7) ^ ((lane >> 3) & 7);   // swizzled source chunk
    const int sx = l15 & 7;                            // read-side XOR key
    const int nbase = seg * (NPOS / NSEG);

    // hoisted per-thread staging pointers (advance by constants per tile)
    const int rq = wv * 16 + (lane >> 3);
    const unsigned short* qsrc0 = Qb + (size_t)(nbase + rq) * CD + csw * 8;
    const unsigned short* qsrc1 = qsrc0 + (size_t)8 * CD;
    const unsigned short* vsrc0 = Vb + (size_t)rq * NPOS + nbase + csw * 8;
    const unsigned short* vsrc1 = vsrc0 + (size_t)8 * NPOS;
    unsigned short* qdst = &Qs[0][(wv * 16) * 64];     // wave-uniform dest
    unsigned short* vdst = &Vs[0][(wv * 16) * 64];

#define STAGE(buf, itv) do {                                                  \
        const size_t qo = (size_t)(itv) * (64 * CD);                          \
        const size_t vo = (size_t)(itv) * 64;                                 \
        gload_lds16(qsrc0 + qo, qdst + (buf) * 4096);                         \
        gload_lds16(qsrc1 + qo, qdst + (buf) * 4096 + 512);                   \
        gload_lds16(vsrc0 + vo, vdst + (buf) * 4096);                         \
        gload_lds16(vsrc1 + vo, vdst + (buf) * 4096 + 512);                   \
    } while (0)

    STAGE(0, 0);

    for (int it = 0; it < NT; ++it) {
        const int cur = it & 1;
        __syncthreads();   // drains stage(cur) DMAs; prev-iter reads done
        if (it + 1 < NT) STAGE(cur ^ 1, it + 1);   // overlaps compute below

        // ---- QK^T: St[row=n_local, col=m] ----
        f32x4_t St[4];
        __builtin_amdgcn_s_setprio(1);
#pragma unroll
        for (int nt = 0; nt < 4; ++nt) {
            const unsigned short* qr = &Qs[cur][(nt * 16 + l15) * 64];
            bf16x8_t a0 = *(const bf16x8_t*)(qr + (g ^ sx) * 8);
            bf16x8_t a1 = *(const bf16x8_t*)(qr + ((4 + g) ^ sx) * 8);
            f32x4_t c = (f32x4_t){0.f, 0.f, 0.f, 0.f};
            c = __builtin_amdgcn_mfma_f32_16x16x32_bf16(a0, bK0, c, 0, 0, 0);
            c = __builtin_amdgcn_mfma_f32_16x16x32_bf16(a1, bK1, c, 0, 0, 0);
            St[nt] = c;
        }
        __builtin_amdgcn_s_setprio(0);

        // ---- online softmax, base-2, defer-max; max3-shaped chains ----
        float tmax = St[0][0];
#pragma unroll
        for (int nt = 0; nt < 4; ++nt) {
            tmax = fmaxf(fmaxf(tmax, St[nt][0]), St[nt][1]);   // -> v_max3
            tmax = fmaxf(fmaxf(tmax, St[nt][2]), St[nt][3]);
        }
        if (!__all(tmax <= mrun + 12.0f)) {
            float tr = fmaxf(tmax, __shfl_xor(tmax, 16));
            tr = fmaxf(tr, __shfl_xor(tr, 32));
            const float mnew = fmaxf(mrun, tr);
            const float corr = __builtin_amdgcn_exp2f(mrun - mnew);
            lsum *= corr;
#pragma unroll
            for (int i = 0; i < 4; ++i) {
                O[i][0] *= corr; O[i][1] *= corr; O[i][2] *= corr; O[i][3] *= corr;
            }
            mrun = mnew;
        }
        unsigned int pw[8];
#pragma unroll
        for (int nt = 0; nt < 4; ++nt) {
            float p0 = __builtin_amdgcn_exp2f(St[nt][0] - mrun);
            float p1 = __builtin_amdgcn_exp2f(St[nt][1] - mrun);
            float p2 = __builtin_amdgcn_exp2f(St[nt][2] - mrun);
            float p3 = __builtin_amdgcn_exp2f(St[nt][3] - mrun);
            lsum += (p0 + p1) + (p2 + p3);
            pw[nt * 2 + 0] = cvtpk_bf16(p0, p1);
            pw[nt * 2 + 1] = cvtpk_bf16(p2, p3);
        }
        // ---- P -> per-wave LDS ----
#pragma unroll
        for (int nt = 0; nt < 4; ++nt)
            *(uint2*)&pl[l15 * 68 + nt * 16 + g * 4] =
                make_uint2(pw[nt * 2], pw[nt * 2 + 1]);

        // ---- PV: O[c,m] += V[c,:] P[m,:] ----
        __builtin_amdgcn_s_setprio(1);
#pragma unroll
        for (int nc = 0; nc < 2; ++nc) {
            union { bf16x8_t v; uint2 d2[2]; } bp;
            bp.d2[0] = *(uint2*)&pl[l15 * 68 + nc * 32 + g * 8];
            bp.d2[1] = *(uint2*)&pl[l15 * 68 + nc * 32 + g * 8 + 4];
#pragma unroll
            for (int ct = 0; ct < 4; ++ct) {
                bf16x8_t av = *(const bf16x8_t*)
                    (&Vs[cur][(ct * 16 + l15) * 64 + (((nc * 4 + g) ^ sx) * 8)]);
                O[ct] = __builtin_amdgcn_mfma_f32_16x16x32_bf16(av, bp.v, O[ct], 0, 0, 0);
            }
        }
        __builtin_amdgcn_s_setprio(0);
    }

    // ---- epilogue: reduce lsum across g, write partials ----
    float lred = lsum + __shfl_xor(lsum, 16);
    lred += __shfl_xor(lred, 32);
    float* Ob = Opart + ((((size_t)att * NB + b) * NSEG + seg) * NPOS) * CD;
    const int m = m0 + l15;
#pragma unroll
    for (int ct = 0; ct < 4; ++ct)
        *(f32x4_t*)(Ob + (size_t)m * CD + ct * 16 + g * 4) = O[ct];
    if (g == 0) {
        float* mlb = ml + ((((size_t)att * NB + b) * NSEG + seg) * NPOS + m) * 2;
        mlb[0] = mrun; mlb[1] = lred;
    }
#undef STAGE
}

// ---------------------------------------------------------------------------
// Combine NSEG partials -> refine = gamma*O/L + resid, bf16 into padded
// layout for the SR conv. grid (256 mtile16, NB, 2 att). Base-2 weights.
// ---------------------------------------------------------------------------
__global__ __launch_bounds__(256) void combine_kernel(
    const float* __restrict__ Opart, const float* __restrict__ ml,
    const float* __restrict__ x, const float* __restrict__ y,
    const float* __restrict__ g1, const float* __restrict__ g2,
    unsigned short* __restrict__ rpadR, unsigned short* __restrict__ rpadI)
{
    const int mt = blockIdx.x, b = blockIdx.y, att = blockIdx.z;
    const float* resid = att ? x : y;
    const float gamma = att ? g2[0] : g1[0];
    unsigned short* rp = (att ? rpadI : rpadR) + (size_t)b * PADN * CD;
    __shared__ float t[64][17];
    const int tt = threadIdx.x;
    {
        const int c = tt >> 2, m4 = (tt & 3) * 4;
        const float4 v = *(const float4*)(resid + ((size_t)b * CD + c) * NPOS + mt * 16 + m4);
        t[c][m4] = v.x; t[c][m4 + 1] = v.y; t[c][m4 + 2] = v.z; t[c][m4 + 3] = v.w;
    }
    __syncthreads();
    const int c = tt & 63, mq = tt >> 6;
    const size_t ob = (((size_t)att * NB + b) * NSEG) * NPOS * CD;
    const size_t mb = (((size_t)att * NB + b) * NSEG) * NPOS;
#pragma unroll
    for (int p = 0; p < 4; ++p) {
        const int mloc = mq * 4 + p;
        const int m = mt * 16 + mloc;
        float mm[NSEG], llv[NSEG];
#pragma unroll
        for (int s = 0; s < NSEG; ++s) {
            mm[s] = ml[(mb + (size_t)s * NPOS + m) * 2];
            llv[s] = ml[(mb + (size_t)s * NPOS + m) * 2 + 1];
        }
        float M = mm[0];
#pragma unroll
        for (int s = 1; s < NSEG; ++s) M = fmaxf(M, mm[s]);
        float Ov = 0.f, L = 0.f;
#pragma unroll
        for (int s = 0; s < NSEG; ++s) {
            const float wgt = __ocml_exp2_f32(mm[s] - M);
            L += wgt * llv[s];
            Ov += wgt * Opart[ob + ((size_t)s * NPOS + m) * CD + c];
        }
        const float val = fmaf(gamma, Ov / L, t[c][mloc]);
        const int h = m >> 6, w_ = m & 63;
        rp[((size_t)((h + 1) * PADW) + (w_ + 1)) * CD + c] = f2bf(val);
    }
}

// ---------------------------------------------------------------------------
extern "C" void kernel_launch(void* const* d_in, const int* in_sizes, int n_in,
                              void* d_out, int out_size, void* d_ws, size_t ws_size,
                              hipStream_t stream)
{
    const float* x    = (const float*)d_in[0];
    const float* y    = (const float*)d_in[1];
    const float* q_w  = (const float*)d_in[2];
    const float* q_s  = (const float*)d_in[3];
    const float* q_b  = (const float*)d_in[4];
    const float* rk_w = (const float*)d_in[5];
    const float* rk_s = (const float*)d_in[6];
    const float* rk_b = (const float*)d_in[7];
    const float* rv_w = (const float*)d_in[8];
    const float* rv_s = (const float*)d_in[9];
    const float* rv_b = (const float*)d_in[10];
    const float* ik_w = (const float*)d_in[11];
    const float* ik_s = (const float*)d_in[12];
    const float* ik_b = (const float*)d_in[13];
    const float* iv_w = (const float*)d_in[14];
    const float* iv_s = (const float*)d_in[15];
    const float* iv_b = (const float*)d_in[16];
    const float* sr_w = (const float*)d_in[17];
    const float* sr_s = (const float*)d_in[18];
    const float* sr_b = (const float*)d_in[19];
    const float* g1   = (const float*)d_in[20];
    const float* g2   = (const float*)d_in[21];

    char* ws = (char*)d_ws;
    size_t off = 0;
    auto alloc = [&](size_t bytes) {
        void* p = ws + off; off += (bytes + 255) & ~(size_t)255; return p;
    };
    const size_t PADB = (size_t)NB * PADN * CD * 2;
    unsigned short* xpad  = (unsigned short*)alloc(PADB);
    unsigned short* ypad  = (unsigned short*)alloc(PADB);
    unsigned short* rpadR = (unsigned short*)alloc(PADB);
    unsigned short* rpadI = (unsigned short*)alloc(PADB);
    unsigned short* Qt  = (unsigned short*)alloc((size_t)NB * NPOS * CD * 2);
    unsigned short* KtR = (unsigned short*)alloc((size_t)NB * NPOS * CD * 2);
    unsigned short* KtI = (unsigned short*)alloc((size_t)NB * NPOS * CD * 2);
    unsigned short* VR  = (unsigned short*)alloc((size_t)NB * NPOS * CD * 2);
    unsigned short* VI  = (unsigned short*)alloc((size_t)NB * NPOS * CD * 2);
    unsigned short* Wf  = (unsigned short*)alloc((size_t)144 * 4 * 64 * 16);
    float* Opart = (float*)alloc((size_t)2 * NB * NSEG * NPOS * CD * 4);
    float* mlb   = (float*)alloc((size_t)2 * NB * NSEG * NPOS * 2 * 4);

    // prep: halo-zero + weight repack + input pack (one launch, no memset)
    prep_kernel<<<dim3(672), 256, 0, stream>>>(
        x, y, q_w, rk_w, rv_w, ik_w, iv_w, sr_w,
        q_s, rk_s, rv_s, ik_s, iv_s, sr_s, xpad, Wf);
    // 5 pre-attention convs (A-LDS + W-LDS), co-split, LAUNCHED TWICE:
    // idempotent duplicate isolates conv cost in the total-time delta.
    conv_mfma_kernel<<<dim3(32, NB, 10), 256, 0, stream>>>(
        xpad, ypad, rpadR, rpadI, Wf,
        q_b, rk_b, rv_b, ik_b, iv_b, sr_b,
        Qt, KtR, VR, KtI, VI, nullptr, 0);
    conv_mfma_kernel<<<dim3(32, NB, 10), 256, 0, stream>>>(
        xpad, ypad, rpadR, rpadI, Wf,
        q_b, rk_b, rv_b, ik_b, iv_b, sr_b,
        Qt, KtR, VR, KtI, VI, nullptr, 0);
    // 64 mblk x 4 b x 2 att x 4 seg = 2048 blocks
    attn_kernel<<<dim3(64 * NB * 2 * NSEG), 256, 0, stream>>>(
        Qt, KtR, KtI, VR, VI, Opart, mlb);
    combine_kernel<<<dim3(256, NB, 2), 256, 0, stream>>>(
        Opart, mlb, x, y, g1, g2, rpadR, rpadI);
    // final SR conv -> d_out fp32 NCHW
    conv_mfma_kernel<<<dim3(32, NB, 2), 256, 0, stream>>>(
        xpad, ypad, rpadR, rpadI, Wf,
        q_b, rk_b, rv_b, ik_b, iv_b, sr_b,
        Qt, KtR, VR, KtI, VI, (float*)d_out, 5);
}

// Round 9
// 177.565 us; speedup vs baseline: 1.5360x; 1.1679x over previous
//
#include <hip/hip_runtime.h>
#include <hip/hip_bf16.h>

#define NPOS 4096          // 64*64 positions
#define CD   64            // channels
#define NB   4             // batch
#define PADW 66
#define PADN (66*66)       // padded positions (zero halo)
#define NSEG 4             // attention n-split
#define NT   (NPOS / NSEG / 64)
#define LOG2E 1.4426950408889634f

extern "C" __device__ float __ocml_exp2_f32(float);

typedef __bf16 bf16x8_t __attribute__((ext_vector_type(8)));
typedef float  f32x4_t  __attribute__((ext_vector_type(4)));
typedef float  f32x16_t __attribute__((ext_vector_type(16)));

static __device__ __forceinline__ unsigned short f2bf(float f) {
    return __builtin_bit_cast(unsigned short, __float2bfloat16(f));
}

static __device__ __forceinline__ void gload_lds16(const void* g, void* l) {
    __builtin_amdgcn_global_load_lds(
        (const __attribute__((address_space(1))) void*)g,
        (__attribute__((address_space(3))) void*)l, 16, 0, 0);
}

static __device__ __forceinline__ unsigned cvtpk_bf16(float lo, float hi) {
    unsigned r;
    asm("v_cvt_pk_bf16_f32 %0, %1, %2" : "=v"(r) : "v"(lo), "v"(hi));
    return r;
}

// ---------------------------------------------------------------------------
// prep: fused {halo-zero, weight-repack, input-pack} in one launch.
// grid 672 = 16 halo + 144 wrepack + 512 pack. block 256.
// ---------------------------------------------------------------------------
__global__ __launch_bounds__(256) void prep_kernel(
    const float* __restrict__ x, const float* __restrict__ y,
    const float* __restrict__ qw, const float* __restrict__ rkw,
    const float* __restrict__ rvw, const float* __restrict__ ikw,
    const float* __restrict__ ivw, const float* __restrict__ srw,
    const float* __restrict__ qs, const float* __restrict__ rks,
    const float* __restrict__ rvs, const float* __restrict__ iks,
    const float* __restrict__ ivs, const float* __restrict__ srs,
    unsigned short* __restrict__ pads, unsigned short* __restrict__ Wf)
{
    const int bx = blockIdx.x;
    if (bx < 16) {
        unsigned short* p = pads + (size_t)bx * PADN * CD;
        const uint4 z = make_uint4(0, 0, 0, 0);
        for (int idx = threadIdx.x; idx < 260 * 8; idx += 256) {
            const int pi = idx >> 3, chn = idx & 7;
            int pos;
            if (pi < 66)       pos = pi;
            else if (pi < 132) pos = 65 * PADW + (pi - 66);
            else { const int rem = pi - 132;
                   pos = (1 + (rem >> 1)) * PADW + ((rem & 1) ? 65 : 0); }
            *(uint4*)(p + (size_t)pos * CD + chn * 8) = z;
        }
        return;
    }
    if (bx < 160) {
        const int f = bx - 16;
        const float* w; const float* s; int cin, local;
        if (f < 36)       { w = qw;  s = qs;  cin = 128; local = f; }
        else if (f < 54)  { w = rkw; s = rks; cin = 64;  local = f - 36; }
        else if (f < 72)  { w = rvw; s = rvs; cin = 64;  local = f - 54; }
        else if (f < 90)  { w = ikw; s = iks; cin = 64;  local = f - 72; }
        else if (f < 108) { w = ivw; s = ivs; cin = 64;  local = f - 90; }
        else              { w = srw; s = srs; cin = 128; local = f - 108; }
        const int src = (cin == 128) ? local / 18 : 0;
        const int rem = (cin == 128) ? local % 18 : local;
        const int tap = rem >> 1, kt = rem & 1;
        const int t = threadIdx.x, cot = t >> 6, l = t & 63;
        const int co = cot * 16 + (l & 15);
        const float kmul = ((f >= 36 && f < 54) || (f >= 72 && f < 90)) ? LOG2E : 1.0f;
        const float sc = s[co] * kmul;
        unsigned short us[8];
#pragma unroll
        for (int e = 0; e < 8; ++e) {
            const int ci = src * 64 + kt * 32 + ((l >> 4) * 8) + e;
            us[e] = f2bf(w[((size_t)co * cin + ci) * 9 + tap] * sc);
        }
        *(uint4*)(Wf + ((size_t)(f * 4 + cot) * 64 + l) * 8) = *(uint4*)us;
        return;
    }
    {
        const int idx = bx - 160;
        const int h = idx & 63, b = (idx >> 6) & 3, src = idx >> 8;
        const float* in = src ? y : x;
        unsigned short* out = pads + (size_t)src * NB * PADN * CD;
        __shared__ float t[64][65];
        const int tt = threadIdx.x;
        {
            const int ci = tt >> 2, w0 = (tt & 3) * 16;
            const float* p = in + ((size_t)b * 64 + ci) * NPOS + h * 64 + w0;
#pragma unroll
            for (int j = 0; j < 16; j += 4) {
                float4 v = *(const float4*)(p + j);
                t[ci][w0 + j] = v.x; t[ci][w0 + j + 1] = v.y;
                t[ci][w0 + j + 2] = v.z; t[ci][w0 + j + 3] = v.w;
            }
        }
        __syncthreads();
        const int w = tt >> 2, c0 = (tt & 3) * 16;
        unsigned short us[16];
#pragma unroll
        for (int j = 0; j < 16; ++j) us[j] = f2bf(t[c0 + j][w]);
        unsigned short* q = out + ((size_t)b * PADN + (h + 1) * PADW + (w + 1)) * CD + c0;
        *(uint4*)q = *(uint4*)us;
        *(uint4*)(q + 8) = *(uint4*)(us + 8);
    }
}

// ---------------------------------------------------------------------------
// Implicit-GEMM conv3x3 via MFMA — A-tile AND weights in LDS (r8 version).
// ---------------------------------------------------------------------------
__global__ __launch_bounds__(256) void conv_mfma_kernel(
    const unsigned short* __restrict__ xpad, const unsigned short* __restrict__ ypad,
    const unsigned short* __restrict__ rpadR, const unsigned short* __restrict__ rpadI,
    const unsigned short* __restrict__ Wf,
    const float* __restrict__ qb, const float* __restrict__ rkb,
    const float* __restrict__ rvb, const float* __restrict__ ikb,
    const float* __restrict__ ivb, const float* __restrict__ srb,
    unsigned short* __restrict__ Qt, unsigned short* __restrict__ KtR,
    unsigned short* __restrict__ VR, unsigned short* __restrict__ KtI,
    unsigned short* __restrict__ VI, float* __restrict__ outf,
    int convid_base)
{
    const int conv = convid_base + (blockIdx.z >> 1);
    const int ch   = blockIdx.z & 1;            // co half
    const int hg = blockIdx.x, b = blockIdx.y;
    const unsigned short *in0, *in1; const float* bias;
    int nsrc, wfbase, layout; void* outp;
    switch (conv) {
        case 0:  in0 = xpad;  in1 = ypad;  nsrc = 2; wfbase = 0;   bias = qb;  outp = Qt;  layout = 0; break;
        case 1:  in0 = xpad;  in1 = 0;     nsrc = 1; wfbase = 36;  bias = rkb; outp = KtR; layout = 0; break;
        case 2:  in0 = xpad;  in1 = 0;     nsrc = 1; wfbase = 54;  bias = rvb; outp = VR;  layout = 1; break;
        case 3:  in0 = ypad;  in1 = 0;     nsrc = 1; wfbase = 72;  bias = ikb; outp = KtI; layout = 0; break;
        case 4:  in0 = ypad;  in1 = 0;     nsrc = 1; wfbase = 90;  bias = ivb; outp = VI;  layout = 1; break;
        default: in0 = rpadR; in1 = rpadI; nsrc = 2; wfbase = 108; bias = srb; outp = outf; layout = 2; break;
    }
    const float bmul = (conv == 1 || conv == 3) ? LOG2E : 1.0f;
    const int tid = threadIdx.x;
    const int lane = tid & 63, wv = tid >> 6;
    const int l15 = lane & 15, g = lane >> 4;
    const int rr = wv >> 1;                     // wave's output row (0/1)
    const int wseg = (wv & 1) * 32;             // wave's pos segment

    __shared__ unsigned short As[264 * 64];     // 4 rows x 66 pos x 64c = 33.8KB
    __shared__ unsigned short Wl[36 * 512];     // 36 slots x 1KB = 36KB

    f32x4_t acc[2][2];                          // [pf][cc]
#pragma unroll
    for (int i = 0; i < 2; ++i)
#pragma unroll
        for (int j = 0; j < 2; ++j) acc[i][j] = (f32x4_t){0.f, 0.f, 0.f, 0.f};

    for (int src = 0; src < nsrc; ++src) {
        if (src) __syncthreads();               // readers of prev src done
        const unsigned short* tsrc =
            (src ? in1 : in0) + ((size_t)b * PADN + (size_t)hg * 2 * PADW) * CD;
        for (int k = 0; k < 2112; k += 256) {
            const int idx = k + tid;
            if (idx < 2112) {                   // wave-uniform tail
                const int s = (idx & ~7) | ((idx ^ (idx >> 3)) & 7);
                gload_lds16(tsrc + (size_t)s * 8, As + (size_t)(idx & ~63) * 8);
            }
        }
#pragma unroll
        for (int j = 0; j < 9; ++j) {
            const int slot = wv * 9 + j;
            const int fg = wfbase + src * 18 + (slot >> 1);
            gload_lds16(Wf + ((size_t)(fg * 4 + ch * 2 + (slot & 1)) * 64 + lane) * 8,
                        Wl + slot * 512);
        }
        __syncthreads();                        // stage visible (vmcnt drained)
#pragma unroll
        for (int ky = 0; ky < 3; ++ky) {
#pragma unroll
            for (int kx = 0; kx < 3; ++kx) {
#pragma unroll
                for (int kt = 0; kt < 2; ++kt) {
                    const int fj = (ky * 3 + kx) * 2 + kt;
                    bf16x8_t a[2];
#pragma unroll
                    for (int pf = 0; pf < 2; ++pf) {
                        const int P = (rr + ky) * 66 + wseg + pf * 16 + kx + l15;
                        const int q = (kt * 4 + g) ^ (P & 7);
                        a[pf] = *(const bf16x8_t*)(As + P * 64 + q * 8);
                    }
#pragma unroll
                    for (int cc = 0; cc < 2; ++cc) {
                        bf16x8_t wfr = *(const bf16x8_t*)(Wl + (size_t)(fj * 2 + cc) * 512 + lane * 8);
                        acc[0][cc] = __builtin_amdgcn_mfma_f32_16x16x32_bf16(a[0], wfr, acc[0][cc], 0, 0, 0);
                        acc[1][cc] = __builtin_amdgcn_mfma_f32_16x16x32_bf16(a[1], wfr, acc[1][cc], 0, 0, 0);
                    }
                }
            }
        }
    }

    const int hrow = hg * 2 + rr;
#pragma unroll
    for (int pf = 0; pf < 2; ++pf) {
        const int nb4 = hrow * 64 + wseg + pf * 16 + g * 4;
        if (layout == 0) {
            unsigned short* o = (unsigned short*)outp + (size_t)b * NPOS * CD;
#pragma unroll
            for (int cc = 0; cc < 2; ++cc) {
                const int co = (ch * 2 + cc) * 16 + l15;
                const float bv = bias[co] * bmul;
#pragma unroll
                for (int r = 0; r < 4; ++r)
                    o[(size_t)(nb4 + r) * CD + co] = f2bf(fmaxf(acc[pf][cc][r] + bv, 0.f));
            }
        } else if (layout == 1) {
            unsigned short* o = (unsigned short*)outp + (size_t)b * CD * NPOS;
#pragma unroll
            for (int cc = 0; cc < 2; ++cc) {
                const int cch = (ch * 2 + cc) * 16 + l15;
                const float bv = bias[cch];
                unsigned short us[4];
#pragma unroll
                for (int r = 0; r < 4; ++r) us[r] = f2bf(fmaxf(acc[pf][cc][r] + bv, 0.f));
                *(uint2*)(o + (size_t)cch * NPOS + nb4) = *(uint2*)us;
            }
        } else {
            float* o = (float*)outp + (size_t)b * CD * NPOS;
#pragma unroll
            for (int cc = 0; cc < 2; ++cc) {
                const int cch = (ch * 2 + cc) * 16 + l15;
                const float bv = bias[cch];
                f32x4_t v;
#pragma unroll
                for (int r = 0; r < 4; ++r) v[r] = fmaxf(acc[pf][cc][r] + bv, 0.f);
                *(f32x4_t*)(o + (size_t)cch * NPOS + nb4) = v;
            }
        }
    }
}

// ---------------------------------------------------------------------------
// Flash attention — 32x32x16 MFMA rewrite.
//   Qt/Kt bf16 [b][n][64]; V bf16 [b][c][n]. K pre-scaled by log2(e).
// 1024 blocks: fid&1=att, (fid>>1)&3=b (fid&7 = XCD group), (fid>>3)&3=seg,
// mblk=fid>>5 (128-m blocks). block 256 = 4 waves x 32 m each.
// Lane (m=l31, hi=l>>5): QK via mfma_32x32x16 (A=Q rows n, B=K cols m,
// persistent K frags) -> lane holds 32 S-values (its hi-half of 64 n) for ONE
// m. Softmax fully per-lane + one shfl_xor(32). P->bf16 via cvt_pk +
// v_permlane32_swap (no LDS round-trip). PV: A=V[c][n] from LDS, B=P frags.
// Q+V double-buffered in LDS (8KB each x2), XOR chunk swizzle (source-side
// pre-swizzle, linear LDS, read chunk q^(row&7)). One __syncthreads/iter.
// Opart fp32 [att][b][seg][m][c]; ml fp32 [att][b][seg][m][2] (base-2 m, l).
// ---------------------------------------------------------------------------
__global__ __launch_bounds__(256, 4) void attn_kernel(
    const unsigned short* __restrict__ Qt,
    const unsigned short* __restrict__ KtR, const unsigned short* __restrict__ KtI,
    const unsigned short* __restrict__ VR,  const unsigned short* __restrict__ VI,
    float* __restrict__ Opart, float* __restrict__ ml)
{
    const int fid = blockIdx.x;
    const int att = fid & 1;
    const int b   = (fid >> 1) & 3;
    const int seg = (fid >> 3) & 3;
    const int mblk = fid >> 5;
    const int lane = threadIdx.x & 63, wv = threadIdx.x >> 6;
    const int l31 = lane & 31, hi = lane >> 5;
    const int m0w = mblk * 128 + wv * 32;       // wave's m base

    const unsigned short* Qb = Qt + (size_t)b * NPOS * CD;
    const unsigned short* Kb = (att ? KtI : KtR) + (size_t)b * NPOS * CD;
    const unsigned short* Vb = (att ? VI : VR) + (size_t)b * CD * NPOS;

    __shared__ unsigned short Qs[2][64 * 64];
    __shared__ unsigned short Vs[2][64 * 64];

    // persistent K B-frags: col m = l31, k = kq*16 + hi*8 + e
    const unsigned short* kbase = Kb + (size_t)(m0w + l31) * CD + hi * 8;
    bf16x8_t fK[4];
#pragma unroll
    for (int kq = 0; kq < 4; ++kq)
        fK[kq] = *(const bf16x8_t*)(kbase + kq * 16);

    f32x16_t Oa, Ob2;
#pragma unroll
    for (int i = 0; i < 16; ++i) { Oa[i] = 0.f; Ob2[i] = 0.f; }
    float mrun = -3.0e38f, lsum = 0.f;

    const int csw = (lane & 7) ^ ((lane >> 3) & 7);   // staging source chunk
    const int nbase = seg * (NPOS / NSEG);

    // staging pointers (identical scheme to r6; per-thread src, uniform dest)
    const int rq = wv * 16 + (lane >> 3);
    const unsigned short* qsrc0 = Qb + (size_t)(nbase + rq) * CD + csw * 8;
    const unsigned short* qsrc1 = qsrc0 + (size_t)8 * CD;
    const unsigned short* vsrc0 = Vb + (size_t)rq * NPOS + nbase + csw * 8;
    const unsigned short* vsrc1 = vsrc0 + (size_t)8 * NPOS;
    unsigned short* qdst = &Qs[0][(wv * 16) * 64];
    unsigned short* vdst = &Vs[0][(wv * 16) * 64];

#define STAGE(buf, itv) do {                                                  \
        const size_t qo = (size_t)(itv) * (64 * CD);                          \
        const size_t vo = (size_t)(itv) * 64;                                 \
        gload_lds16(qsrc0 + qo, qdst + (buf) * 4096);                         \
        gload_lds16(qsrc1 + qo, qdst + (buf) * 4096 + 512);                   \
        gload_lds16(vsrc0 + vo, vdst + (buf) * 4096);                         \
        gload_lds16(vsrc1 + vo, vdst + (buf) * 4096 + 512);                   \
    } while (0)

    STAGE(0, 0);

    const int r0x = l31 & 7;                    // read-XOR key (row&7, both nb)

    for (int it = 0; it < NT; ++it) {
        const int cur = it & 1;
        __syncthreads();   // drains stage(cur) DMAs; prev-iter reads done
        if (it + 1 < NT) STAGE(cur ^ 1, it + 1);

        // ---- QK^T: St[n][m], A = Q rows n (two 32-blocks), B = fK ----
        f32x16_t StA, StB;
#pragma unroll
        for (int i = 0; i < 16; ++i) { StA[i] = 0.f; StB[i] = 0.f; }
        const unsigned short* qsl = Qs[cur];
        __builtin_amdgcn_s_setprio(1);
#pragma unroll
        for (int kq = 0; kq < 4; ++kq) {
            const int chunk = ((kq << 1) | hi) ^ r0x;
            bf16x8_t a0 = *(const bf16x8_t*)(qsl + (size_t)l31 * 64 + chunk * 8);
            bf16x8_t a1 = *(const bf16x8_t*)(qsl + (size_t)(32 + l31) * 64 + chunk * 8);
            StA = __builtin_amdgcn_mfma_f32_32x32x16_bf16(a0, fK[kq], StA, 0, 0, 0);
            StB = __builtin_amdgcn_mfma_f32_32x32x16_bf16(a1, fK[kq], StB, 0, 0, 0);
        }
        __builtin_amdgcn_s_setprio(0);

        // ---- online softmax (base-2, defer-max); lane owns m = m0w+l31 ----
        float tmax = StA[0];
#pragma unroll
        for (int r = 0; r < 16; r += 2)
            tmax = fmaxf(fmaxf(tmax, StA[r]), StA[r + 1]);
#pragma unroll
        for (int r = 0; r < 16; r += 2)
            tmax = fmaxf(fmaxf(tmax, StB[r]), StB[r + 1]);
        if (!__all(tmax <= mrun + 12.0f)) {
            const float tr = fmaxf(tmax, __shfl_xor(tmax, 32));
            const float mnew = fmaxf(mrun, tr);
            const float corr = __builtin_amdgcn_exp2f(mrun - mnew);
            lsum *= corr;
#pragma unroll
            for (int i = 0; i < 16; ++i) { Oa[i] *= corr; Ob2[i] *= corr; }
            mrun = mnew;
        }

        // ---- exp + pack to PV B-frags via cvt_pk + permlane32_swap ----
        // St reg r (q=r>>2,s=r&3) <-> n = nb*32 + 8q + 4hi + s.
        // frag[nq=nb*2+hf] slots: [own q=2hf | partner q=2hf] for hi=0,
        //                         [partner q=2hf+1 | own q=2hf+1] for hi=1.
        unsigned fr[4][4];
#pragma unroll
        for (int nb = 0; nb < 2; ++nb) {
            float p[16];
#pragma unroll
            for (int r = 0; r < 16; ++r) {
                p[r] = __builtin_amdgcn_exp2f((nb ? StB[r] : StA[r]) - mrun);
                lsum += p[r];
            }
#pragma unroll
            for (int hf = 0; hf < 2; ++hf) {
                unsigned u0 = cvtpk_bf16(p[8 * hf + 0], p[8 * hf + 1]);
                unsigned u1 = cvtpk_bf16(p[8 * hf + 2], p[8 * hf + 3]);
                unsigned v0 = cvtpk_bf16(p[8 * hf + 4], p[8 * hf + 5]);
                unsigned v1 = cvtpk_bf16(p[8 * hf + 6], p[8 * hf + 7]);
                asm volatile("v_permlane32_swap_b32 %0, %1" : "+v"(u0), "+v"(v0));
                asm volatile("v_permlane32_swap_b32 %0, %1" : "+v"(u1), "+v"(v1));
                fr[nb * 2 + hf][0] = u0; fr[nb * 2 + hf][1] = u1;
                fr[nb * 2 + hf][2] = v0; fr[nb * 2 + hf][3] = v1;
            }
        }

        // ---- PV: O[c][m] += V[c][n] P[m][n]; A = V rows c from LDS ----
        const unsigned short* vsl = Vs[cur];
        __builtin_amdgcn_s_setprio(1);
#pragma unroll
        for (int nq = 0; nq < 4; ++nq) {
            union { unsigned u[4]; bf16x8_t v; } bfr;
            bfr.u[0] = fr[nq][0]; bfr.u[1] = fr[nq][1];
            bfr.u[2] = fr[nq][2]; bfr.u[3] = fr[nq][3];
            const int chunk = ((nq << 1) | hi) ^ r0x;
            bf16x8_t av0 = *(const bf16x8_t*)(vsl + (size_t)l31 * 64 + chunk * 8);
            bf16x8_t av1 = *(const bf16x8_t*)(vsl + (size_t)(32 + l31) * 64 + chunk * 8);
            Oa  = __builtin_amdgcn_mfma_f32_32x32x16_bf16(av0, bfr.v, Oa, 0, 0, 0);
            Ob2 = __builtin_amdgcn_mfma_f32_32x32x16_bf16(av1, bfr.v, Ob2, 0, 0, 0);
        }
        __builtin_amdgcn_s_setprio(0);
    }

    // ---- epilogue ----
    const float lred = lsum + __shfl_xor(lsum, 32);
    const int m = m0w + l31;
    float* Obase = Opart + ((((size_t)att * NB + b) * NSEG + seg) * NPOS + m) * CD;
#pragma unroll
    for (int q = 0; q < 4; ++q) {
        f32x4_t w0, w1;
#pragma unroll
        for (int j = 0; j < 4; ++j) { w0[j] = Oa[4 * q + j]; w1[j] = Ob2[4 * q + j]; }
        *(f32x4_t*)(Obase + 8 * q + 4 * hi) = w0;
        *(f32x4_t*)(Obase + 32 + 8 * q + 4 * hi) = w1;
    }
    if (hi == 0) {
        float* mlb = ml + ((((size_t)att * NB + b) * NSEG + seg) * NPOS + m) * 2;
        mlb[0] = mrun; mlb[1] = lred;
    }
#undef STAGE
}

// ---------------------------------------------------------------------------
// Combine NSEG partials -> refine = gamma*O/L + resid, bf16 into padded
// layout for the SR conv. grid (256 mtile16, NB, 2 att). Base-2 weights.
// ---------------------------------------------------------------------------
__global__ __launch_bounds__(256) void combine_kernel(
    const float* __restrict__ Opart, const float* __restrict__ ml,
    const float* __restrict__ x, const float* __restrict__ y,
    const float* __restrict__ g1, const float* __restrict__ g2,
    unsigned short* __restrict__ rpadR, unsigned short* __restrict__ rpadI)
{
    const int mt = blockIdx.x, b = blockIdx.y, att = blockIdx.z;
    const float* resid = att ? x : y;
    const float gamma = att ? g2[0] : g1[0];
    unsigned short* rp = (att ? rpadI : rpadR) + (size_t)b * PADN * CD;
    __shared__ float t[64][17];
    const int tt = threadIdx.x;
    {
        const int c = tt >> 2, m4 = (tt & 3) * 4;
        const float4 v = *(const float4*)(resid + ((size_t)b * CD + c) * NPOS + mt * 16 + m4);
        t[c][m4] = v.x; t[c][m4 + 1] = v.y; t[c][m4 + 2] = v.z; t[c][m4 + 3] = v.w;
    }
    __syncthreads();
    const int c = tt & 63, mq = tt >> 6;
    const size_t ob = (((size_t)att * NB + b) * NSEG) * NPOS * CD;
    const size_t mb = (((size_t)att * NB + b) * NSEG) * NPOS;
#pragma unroll
    for (int p = 0; p < 4; ++p) {
        const int mloc = mq * 4 + p;
        const int m = mt * 16 + mloc;
        float mm[NSEG], llv[NSEG];
#pragma unroll
        for (int s = 0; s < NSEG; ++s) {
            mm[s] = ml[(mb + (size_t)s * NPOS + m) * 2];
            llv[s] = ml[(mb + (size_t)s * NPOS + m) * 2 + 1];
        }
        float M = mm[0];
#pragma unroll
        for (int s = 1; s < NSEG; ++s) M = fmaxf(M, mm[s]);
        float Ov = 0.f, L = 0.f;
#pragma unroll
        for (int s = 0; s < NSEG; ++s) {
            const float wgt = __ocml_exp2_f32(mm[s] - M);
            L += wgt * llv[s];
            Ov += wgt * Opart[ob + ((size_t)s * NPOS + m) * CD + c];
        }
        const float val = fmaf(gamma, Ov / L, t[c][mloc]);
        const int h = m >> 6, w_ = m & 63;
        rp[((size_t)((h + 1) * PADW) + (w_ + 1)) * CD + c] = f2bf(val);
    }
}

// ---------------------------------------------------------------------------
extern "C" void kernel_launch(void* const* d_in, const int* in_sizes, int n_in,
                              void* d_out, int out_size, void* d_ws, size_t ws_size,
                              hipStream_t stream)
{
    const float* x    = (const float*)d_in[0];
    const float* y    = (const float*)d_in[1];
    const float* q_w  = (const float*)d_in[2];
    const float* q_s  = (const float*)d_in[3];
    const float* q_b  = (const float*)d_in[4];
    const float* rk_w = (const float*)d_in[5];
    const float* rk_s = (const float*)d_in[6];
    const float* rk_b = (const float*)d_in[7];
    const float* rv_w = (const float*)d_in[8];
    const float* rv_s = (const float*)d_in[9];
    const float* rv_b = (const float*)d_in[10];
    const float* ik_w = (const float*)d_in[11];
    const float* ik_s = (const float*)d_in[12];
    const float* ik_b = (const float*)d_in[13];
    const float* iv_w = (const float*)d_in[14];
    const float* iv_s = (const float*)d_in[15];
    const float* iv_b = (const float*)d_in[16];
    const float* sr_w = (const float*)d_in[17];
    const float* sr_s = (const float*)d_in[18];
    const float* sr_b = (const float*)d_in[19];
    const float* g1   = (const float*)d_in[20];
    const float* g2   = (const float*)d_in[21];

    char* ws = (char*)d_ws;
    size_t off = 0;
    auto alloc = [&](size_t bytes) {
        void* p = ws + off; off += (bytes + 255) & ~(size_t)255; return p;
    };
    const size_t PADB = (size_t)NB * PADN * CD * 2;
    unsigned short* xpad  = (unsigned short*)alloc(PADB);
    unsigned short* ypad  = (unsigned short*)alloc(PADB);
    unsigned short* rpadR = (unsigned short*)alloc(PADB);
    unsigned short* rpadI = (unsigned short*)alloc(PADB);
    unsigned short* Qt  = (unsigned short*)alloc((size_t)NB * NPOS * CD * 2);
    unsigned short* KtR = (unsigned short*)alloc((size_t)NB * NPOS * CD * 2);
    unsigned short* KtI = (unsigned short*)alloc((size_t)NB * NPOS * CD * 2);
    unsigned short* VR  = (unsigned short*)alloc((size_t)NB * NPOS * CD * 2);
    unsigned short* VI  = (unsigned short*)alloc((size_t)NB * NPOS * CD * 2);
    unsigned short* Wf  = (unsigned short*)alloc((size_t)144 * 4 * 64 * 16);
    float* Opart = (float*)alloc((size_t)2 * NB * NSEG * NPOS * CD * 4);
    float* mlb   = (float*)alloc((size_t)2 * NB * NSEG * NPOS * 2 * 4);

    // prep: halo-zero + weight repack + input pack (one launch, no memset)
    prep_kernel<<<dim3(672), 256, 0, stream>>>(
        x, y, q_w, rk_w, rv_w, ik_w, iv_w, sr_w,
        q_s, rk_s, rv_s, ik_s, iv_s, sr_s, xpad, Wf);
    // 5 pre-attention convs (A-LDS + W-LDS), co-split
    conv_mfma_kernel<<<dim3(32, NB, 10), 256, 0, stream>>>(
        xpad, ypad, rpadR, rpadI, Wf,
        q_b, rk_b, rv_b, ik_b, iv_b, sr_b,
        Qt, KtR, VR, KtI, VI, nullptr, 0);
    // 32 mblk x 4 b x 2 att x 4 seg = 1024 blocks (128-m blocks)
    attn_kernel<<<dim3(32 * NB * 2 * NSEG), 256, 0, stream>>>(
        Qt, KtR, KtI, VR, VI, Opart, mlb);
    combine_kernel<<<dim3(256, NB, 2), 256, 0, stream>>>(
        Opart, mlb, x, y, g1, g2, rpadR, rpadI);
    // final SR conv -> d_out fp32 NCHW
    conv_mfma_kernel<<<dim3(32, NB, 2), 256, 0, stream>>>(
        xpad, ypad, rpadR, rpadI, Wf,
        q_b, rk_b, rv_b, ik_b, iv_b, sr_b,
        Qt, KtR, VR, KtI, VI, (float*)d_out, 5);
}